// Round 1
// baseline (557.021 us; speedup 1.0000x reference)
//
#include <hip/hip_runtime.h>
#include <hip/hip_bf16.h>
#include <math.h>

#define B_ 4
#define S_ 2048
#define D_ 512
#define H_ 8
#define K_ 512
#define F_ 2048
#define NT 8192     // B*S tokens
#define HK 4096     // H*K
#define HG 2        // heads per group
#define NGROUP 4    // H/HG
#define GN 1024     // HG*K columns per group

typedef __attribute__((ext_vector_type(8))) short bf16x8;
typedef __attribute__((ext_vector_type(4))) float f32x4;
typedef unsigned short u16;

__device__ __forceinline__ float bits2f(u16 b) {
  union { unsigned u; float f; } c; c.u = ((unsigned)b) << 16; return c.f;
}
__device__ __forceinline__ u16 f2bfbits(float f) {
  union { float f; unsigned u; } c; c.f = f;
  unsigned r = c.u + 0x7fffu + ((c.u >> 16) & 1u);
  return (u16)(r >> 16);
}

__device__ __forceinline__ void gload16(const void* g, void* lds) {
  __builtin_amdgcn_global_load_lds(
      (const __attribute__((address_space(1))) unsigned int*)g,
      (__attribute__((address_space(3))) unsigned int*)lds, 16, 0, 0);
}

// ---------------------------------------------------------------------------
// fp32 -> bf16 elementwise (x conversion)
// ---------------------------------------------------------------------------
__global__ __launch_bounds__(256) void conv_f32_bf16(const float* __restrict__ in,
                                                     u16* __restrict__ out, int n4) {
  int i = blockIdx.x * 256 + threadIdx.x;
  if (i < n4) {
    float4 f = ((const float4*)in)[i];
    ushort4 o;
    o.x = f2bfbits(f.x); o.y = f2bfbits(f.y); o.z = f2bfbits(f.z); o.w = f2bfbits(f.w);
    ((ushort4*)out)[i] = o;
  }
}

// ---------------------------------------------------------------------------
// fp32 (rows x cols) -> bf16 transposed (cols x rows)
// ---------------------------------------------------------------------------
__global__ __launch_bounds__(256) void transpose_f32_bf16(const float* __restrict__ in,
                                                          u16* __restrict__ out,
                                                          int rows, int cols) {
  __shared__ float tile[32][33];
  const int tx = threadIdx.x & 31;
  const int ty = threadIdx.x >> 5;          // 0..7
  const int rb = blockIdx.y * 32;
  const int cb = blockIdx.x * 32;
  for (int i = ty; i < 32; i += 8)
    tile[i][tx] = in[(size_t)(rb + i) * cols + cb + tx];
  __syncthreads();
  for (int i = ty; i < 32; i += 8)
    out[(size_t)(cb + i) * rows + rb + tx] = f2bfbits(tile[tx][i]);
}

// ---------------------------------------------------------------------------
// bf16 GEMM: C[M,N] = A[M,Kd] * Bt[N,Kd]^T (+bias) (gelu?) (+=Cf?)
// 128x128 tile, BK=64, 4 waves (2x2 of 64x64), mfma 16x16x32 bf16.
// ---------------------------------------------------------------------------
template <int BIAS, int GELU, int ACC, int OUTBF>
__global__ __launch_bounds__(256) void gemm128(const u16* __restrict__ A, int lda,
                                               const u16* __restrict__ Bt, int ldb,
                                               const float* __restrict__ bias,
                                               float* __restrict__ Cf,
                                               u16* __restrict__ Cb, int ldc, int Kd) {
  __shared__ short sA[128 * 64];
  __shared__ short sB[128 * 64];
  const int tid = threadIdx.x;
  const int lane = tid & 63;
  const int wave = tid >> 6;
  const int bm = blockIdx.x * 128;
  const int bn = blockIdx.y * 128;
  const int wr = (wave >> 1) * 64;
  const int wc = (wave & 1) * 64;

  f32x4 acc[4][4] = {};

  const int srow = wave * 32 + (lane >> 3);     // staging row within tile
  const int scol = (lane & 7) * 8;              // staging col (elements)
  const u16* ag = A + (size_t)(bm + srow) * lda + scol;
  const u16* bg = Bt + (size_t)(bn + srow) * ldb + scol;
  short* sAw = &sA[(wave * 32) * 64];
  short* sBw = &sB[(wave * 32) * 64];

  for (int kt = 0; kt < Kd; kt += 64) {
    for (int j = 0; j < 4; ++j) {
      gload16(ag + (size_t)j * 8 * lda + kt, sAw + j * 8 * 64);
      gload16(bg + (size_t)j * 8 * ldb + kt, sBw + j * 8 * 64);
    }
    __syncthreads();
    for (int kk = 0; kk < 64; kk += 32) {
      const int ko = kk + (lane >> 4) * 8;
      bf16x8 af[4], bfr[4];
#pragma unroll
      for (int m = 0; m < 4; ++m)
        af[m] = *(const bf16x8*)&sA[(wr + m * 16 + (lane & 15)) * 64 + ko];
#pragma unroll
      for (int n = 0; n < 4; ++n)
        bfr[n] = *(const bf16x8*)&sB[(wc + n * 16 + (lane & 15)) * 64 + ko];
#pragma unroll
      for (int m = 0; m < 4; ++m)
#pragma unroll
        for (int n = 0; n < 4; ++n)
          acc[m][n] = __builtin_amdgcn_mfma_f32_16x16x32_bf16(af[m], bfr[n], acc[m][n], 0, 0, 0);
    }
    __syncthreads();
  }

#pragma unroll
  for (int m = 0; m < 4; ++m) {
    const int row0 = bm + wr + m * 16 + (lane >> 4) * 4;
#pragma unroll
    for (int n = 0; n < 4; ++n) {
      const int col = bn + wc + n * 16 + (lane & 15);
      float badd = BIAS ? bias[col] : 0.f;
      f32x4 a4 = acc[m][n];
#pragma unroll
      for (int r = 0; r < 4; ++r) {
        float vv = a4[r] + badd;
        if (GELU) vv = 0.5f * vv * (1.f + erff(vv * 0.70710678118f));
        size_t idx = (size_t)(row0 + r) * ldc + col;
        if (ACC) vv += Cf[idx];
        if (OUTBF) Cb[idx] = f2bfbits(vv);
        else Cf[idx] = vv;
      }
    }
  }
}

// ---------------------------------------------------------------------------
// Windowed (tridiagonal) attention for one head-group.
// One wave per (token, head-in-group). q,k,v,ctx: (NT, GN) bf16.
// ---------------------------------------------------------------------------
__global__ __launch_bounds__(256) void attn_window(const u16* __restrict__ q,
                                                   const u16* __restrict__ k,
                                                   const u16* __restrict__ v,
                                                   u16* __restrict__ ctx) {
  const int lane = threadIdx.x & 63;
  const int gw = blockIdx.x * 4 + (threadIdx.x >> 6);
  const int hh = gw % HG;
  const int t = gw / HG;
  const int s = t % S_;
  const size_t base = (size_t)t * GN + hh * K_ + lane * 8;

  float qf[8];
  {
    bf16x8 q8 = *(const bf16x8*)(q + base);
#pragma unroll
    for (int e = 0; e < 8; ++e) qf[e] = bits2f((u16)q8[e]);
  }

  const bool val0 = (s > 0), val2 = (s < S_ - 1);
  float dot[3] = {0.f, 0.f, 0.f};
  float vf[3][8];
#pragma unroll
  for (int j = 0; j < 3; ++j) {
    if ((j == 0 && !val0) || (j == 2 && !val2)) continue;
    const size_t nb = base + (size_t)(j - 1) * GN;
    bf16x8 k8 = *(const bf16x8*)(k + nb);
    bf16x8 v8 = *(const bf16x8*)(v + nb);
    float d = 0.f;
#pragma unroll
    for (int e = 0; e < 8; ++e) {
      d += qf[e] * bits2f((u16)k8[e]);
      vf[j][e] = bits2f((u16)v8[e]);
    }
    dot[j] = d;
  }
#pragma unroll
  for (int j = 0; j < 3; ++j) {
    float d = dot[j];
    for (int m = 32; m >= 1; m >>= 1) d += __shfl_xor(d, m);
    dot[j] = d;
  }
  const float scale = 0.044194173824159f;  // 1/sqrt(512)
  float sc[3];
  sc[0] = val0 ? dot[0] * scale : -1e30f;
  sc[1] = dot[1] * scale;
  sc[2] = val2 ? dot[2] * scale : -1e30f;
  float mx = fmaxf(sc[0], fmaxf(sc[1], sc[2]));
  float p[3], sum = 0.f;
#pragma unroll
  for (int j = 0; j < 3; ++j) {
    p[j] = (sc[j] > -1e29f) ? expf(sc[j] - mx) : 0.f;
    sum += p[j];
  }
  const float inv = 1.f / sum;
  float o[8] = {0.f, 0.f, 0.f, 0.f, 0.f, 0.f, 0.f, 0.f};
#pragma unroll
  for (int j = 0; j < 3; ++j) {
    if ((j == 0 && !val0) || (j == 2 && !val2)) continue;
    const float pj = p[j] * inv;
#pragma unroll
    for (int e = 0; e < 8; ++e) o[e] += pj * vf[j][e];
  }
  bf16x8 o8;
#pragma unroll
  for (int e = 0; e < 8; ++e) o8[e] = (short)f2bfbits(o[e]);
  *(bf16x8*)(ctx + base) = o8;
}

// ---------------------------------------------------------------------------
// y = xres + yadd (+bias); out = LN(y)*gamma+beta -> fp32 (and optional bf16)
// one block (256 thr) per row of D=512
// ---------------------------------------------------------------------------
__global__ __launch_bounds__(256) void resid_ln(const float* __restrict__ xres,
                                                const float* __restrict__ yadd,
                                                const float* __restrict__ bias,
                                                const float* __restrict__ gamma,
                                                const float* __restrict__ beta,
                                                float* __restrict__ outf,
                                                u16* __restrict__ outb) {
  const int row = blockIdx.x;
  const int tid = threadIdx.x;
  const size_t base = (size_t)row * D_;
  float2 xv = ((const float2*)(xres + base))[tid];
  float2 yv = ((const float2*)(yadd + base))[tid];
  float y0 = xv.x + yv.x, y1 = xv.y + yv.y;
  if (bias) {
    float2 bv = ((const float2*)bias)[tid];
    y0 += bv.x; y1 += bv.y;
  }
  float s = y0 + y1, ss = y0 * y0 + y1 * y1;
  for (int m = 32; m >= 1; m >>= 1) { s += __shfl_xor(s, m); ss += __shfl_xor(ss, m); }
  __shared__ float red[8];
  const int wave = tid >> 6, lane = tid & 63;
  if (lane == 0) { red[wave] = s; red[4 + wave] = ss; }
  __syncthreads();
  s = red[0] + red[1] + red[2] + red[3];
  ss = red[4] + red[5] + red[6] + red[7];
  const float mean = s * (1.f / D_);
  const float var = ss * (1.f / D_) - mean * mean;
  const float rstd = rsqrtf(var + 1e-3f);
  float2 gv = ((const float2*)gamma)[tid];
  float2 bev = ((const float2*)beta)[tid];
  float o0 = (y0 - mean) * rstd * gv.x + bev.x;
  float o1 = (y1 - mean) * rstd * gv.y + bev.y;
  if (outf) { float2 of; of.x = o0; of.y = o1; ((float2*)(outf + base))[tid] = of; }
  if (outb) { ushort2 ob; ob.x = f2bfbits(o0); ob.y = f2bfbits(o1); ((ushort2*)(outb + base))[tid] = ob; }
}

// ---------------------------------------------------------------------------
extern "C" void kernel_launch(void* const* d_in, const int* in_sizes, int n_in,
                              void* d_out, int out_size, void* d_ws, size_t ws_size,
                              hipStream_t stream) {
  const float* x  = (const float*)d_in[0];
  const float* Wq = (const float*)d_in[1];
  const float* bq = (const float*)d_in[2];
  const float* Wk = (const float*)d_in[3];
  const float* bk = (const float*)d_in[4];
  const float* Wv = (const float*)d_in[5];
  const float* bv = (const float*)d_in[6];
  const float* Wo = (const float*)d_in[7];
  const float* bo = (const float*)d_in[8];
  const float* W1 = (const float*)d_in[9];
  const float* b1 = (const float*)d_in[10];
  const float* W2 = (const float*)d_in[11];
  const float* b2 = (const float*)d_in[12];
  const float* g1 = (const float*)d_in[13];
  const float* be1 = (const float*)d_in[14];
  const float* g2 = (const float*)d_in[15];
  const float* be2 = (const float*)d_in[16];
  float* out = (float*)d_out;

  char* w = (char*)d_ws;
  size_t o = 0;
  auto nxt = [&](size_t bytes) -> char* {
    char* p = w + o;
    o += (bytes + 255) & ~(size_t)255;
    return p;
  };
  u16* xb    = (u16*)nxt((size_t)NT * D_ * 2);
  u16* wqt   = (u16*)nxt((size_t)HK * D_ * 2);
  u16* wkt   = (u16*)nxt((size_t)HK * D_ * 2);
  u16* wvt   = (u16*)nxt((size_t)HK * D_ * 2);
  u16* wot   = (u16*)nxt((size_t)D_ * HK * 2);
  u16* w1t   = (u16*)nxt((size_t)F_ * D_ * 2);
  u16* w2t   = (u16*)nxt((size_t)D_ * F_ * 2);
  u16* qg    = (u16*)nxt((size_t)NT * GN * 2);
  u16* kg    = (u16*)nxt((size_t)NT * GN * 2);
  u16* vg    = (u16*)nxt((size_t)NT * GN * 2);
  u16* ctxg  = (u16*)nxt((size_t)NT * GN * 2);
  float* attnf = (float*)nxt((size_t)NT * D_ * 4);
  float* out1f = (float*)nxt((size_t)NT * D_ * 4);
  u16* out1b   = (u16*)nxt((size_t)NT * D_ * 2);
  u16* hb      = (u16*)nxt((size_t)NT * F_ * 2);
  float* ffnf  = (float*)nxt((size_t)NT * D_ * 4);

  // --- conversions ---
  conv_f32_bf16<<<dim3(NT * D_ / 4 / 256), 256, 0, stream>>>(x, xb, NT * D_ / 4);
  transpose_f32_bf16<<<dim3(HK / 32, D_ / 32), 256, 0, stream>>>(Wq, wqt, D_, HK);
  transpose_f32_bf16<<<dim3(HK / 32, D_ / 32), 256, 0, stream>>>(Wk, wkt, D_, HK);
  transpose_f32_bf16<<<dim3(HK / 32, D_ / 32), 256, 0, stream>>>(Wv, wvt, D_, HK);
  transpose_f32_bf16<<<dim3(D_ / 32, HK / 32), 256, 0, stream>>>(Wo, wot, HK, D_);
  transpose_f32_bf16<<<dim3(F_ / 32, D_ / 32), 256, 0, stream>>>(W1, w1t, D_, F_);
  transpose_f32_bf16<<<dim3(D_ / 32, F_ / 32), 256, 0, stream>>>(W2, w2t, F_, D_);

  hipMemsetAsync(attnf, 0, (size_t)NT * D_ * 4, stream);

  // --- attention by head-groups ---
  for (int g = 0; g < NGROUP; ++g) {
    const u16* wqts = wqt + (size_t)g * GN * D_;
    const u16* wkts = wkt + (size_t)g * GN * D_;
    const u16* wvts = wvt + (size_t)g * GN * D_;
    gemm128<1, 0, 0, 1><<<dim3(NT / 128, GN / 128), 256, 0, stream>>>(
        xb, D_, wqts, D_, bq + g * GN, nullptr, qg, GN, D_);
    gemm128<1, 0, 0, 1><<<dim3(NT / 128, GN / 128), 256, 0, stream>>>(
        xb, D_, wkts, D_, bk + g * GN, nullptr, kg, GN, D_);
    gemm128<1, 0, 0, 1><<<dim3(NT / 128, GN / 128), 256, 0, stream>>>(
        xb, D_, wvts, D_, bv + g * GN, nullptr, vg, GN, D_);
    attn_window<<<dim3(NT * HG / 4), 256, 0, stream>>>(qg, kg, vg, ctxg);
    // attnf += ctxg @ Wo[group rows]
    gemm128<0, 0, 1, 0><<<dim3(NT / 128, D_ / 128), 256, 0, stream>>>(
        ctxg, GN, wot + g * GN, HK, nullptr, attnf, nullptr, D_, GN);
  }

  // --- LN1: out1 = LN(x + attn + bo) ---
  resid_ln<<<dim3(NT), 256, 0, stream>>>(x, attnf, bo, g1, be1, out1f, out1b);

  // --- FFN ---
  gemm128<1, 1, 0, 1><<<dim3(NT / 128, F_ / 128), 256, 0, stream>>>(
      out1b, D_, w1t, D_, b1, nullptr, hb, F_, D_);
  gemm128<1, 0, 0, 0><<<dim3(NT / 128, D_ / 128), 256, 0, stream>>>(
      hb, F_, w2t, F_, b2, ffnf, nullptr, D_, F_);

  // --- LN2: out = LN(out1 + ffn) ---
  resid_ln<<<dim3(NT), 256, 0, stream>>>(out1f, ffnf, nullptr, g2, be2, out, nullptr);

  (void)in_sizes; (void)n_in; (void)out_size; (void)ws_size;
}

// Round 2
// 504.450 us; speedup vs baseline: 1.1042x; 1.1042x over previous
//
#include <hip/hip_runtime.h>
#include <hip/hip_bf16.h>
#include <math.h>

#define B_ 4
#define S_ 2048
#define D_ 512
#define H_ 8
#define K_ 512
#define F_ 2048
#define NT 8192     // B*S tokens
#define HK 4096     // H*K
#define HG 2        // heads per group
#define NGROUP 4    // H/HG
#define GN 1024     // HG*K columns per group
#define G3 3072     // 3*GN

typedef __attribute__((ext_vector_type(8))) short bf16x8;
typedef __attribute__((ext_vector_type(4))) float f32x4;
typedef unsigned short u16;

__device__ __forceinline__ float bits2f(u16 b) {
  union { unsigned u; float f; } c; c.u = ((unsigned)b) << 16; return c.f;
}
__device__ __forceinline__ u16 f2bfbits(float f) {
  union { float f; unsigned u; } c; c.f = f;
  unsigned r = c.u + 0x7fffu + ((c.u >> 16) & 1u);
  return (u16)(r >> 16);
}

__device__ __forceinline__ void gload16(const void* g, void* lds) {
  __builtin_amdgcn_global_load_lds(
      (const __attribute__((address_space(1))) unsigned int*)g,
      (__attribute__((address_space(3))) unsigned int*)lds, 16, 0, 0);
}

// ---------------------------------------------------------------------------
// fp32 -> bf16 elementwise (x conversion)
// ---------------------------------------------------------------------------
__global__ __launch_bounds__(256) void conv_f32_bf16(const float* __restrict__ in,
                                                     u16* __restrict__ out, int n4) {
  int i = blockIdx.x * 256 + threadIdx.x;
  if (i < n4) {
    float4 f = ((const float4*)in)[i];
    ushort4 o;
    o.x = f2bfbits(f.x); o.y = f2bfbits(f.y); o.z = f2bfbits(f.z); o.w = f2bfbits(f.w);
    ((ushort4*)out)[i] = o;
  }
}

// ---------------------------------------------------------------------------
// fp32 (rows x cols, leading dim ldin) -> bf16 transposed (cols x rows)
// in may be pre-offset to a column block; out has leading dim = rows.
// ---------------------------------------------------------------------------
__global__ __launch_bounds__(256) void transpose_f32_bf16(const float* __restrict__ in,
                                                          int ldin,
                                                          u16* __restrict__ out,
                                                          int rows, int cols) {
  __shared__ float tile[32][33];
  const int tx = threadIdx.x & 31;
  const int ty = threadIdx.x >> 5;          // 0..7
  const int rb = blockIdx.y * 32;
  const int cb = blockIdx.x * 32;
  for (int i = ty; i < 32; i += 8)
    tile[i][tx] = in[(size_t)(rb + i) * ldin + cb + tx];
  __syncthreads();
  for (int i = ty; i < 32; i += 8)
    out[(size_t)(cb + i) * rows + rb + tx] = f2bfbits(tile[tx][i]);
}

// ---------------------------------------------------------------------------
// concat per-group qkv bias: o[g][part][GN], part 0=q 1=k 2=v
// ---------------------------------------------------------------------------
__global__ __launch_bounds__(256) void qkv_bias_cat(const float* __restrict__ bq,
                                                    const float* __restrict__ bk,
                                                    const float* __restrict__ bv,
                                                    float* __restrict__ o) {
  int i = blockIdx.x * 256 + threadIdx.x;   // < NGROUP*G3
  int g = i / G3, r = i % G3;
  int part = r / GN, off = r % GN;
  const float* src = (part == 0) ? bq : (part == 1) ? bk : bv;
  o[i] = src[g * GN + off];
}

// ---------------------------------------------------------------------------
// bf16 GEMM: C[M,N] = A[M,Kd] * Bt[N,Kd]^T (+bias) (gelu?)
// 128x128 tile, BK=64, 4 waves (2x2 of 64x64), mfma 16x16x32 bf16.
// LDS XOR-swizzled (T2) via pre-swizzled global source (rule 21).
// OUT: 0 = f32 store, 1 = bf16 store, 2 = f32 atomicAdd (split-K over z).
// ---------------------------------------------------------------------------
template <int BIAS, int GELU, int OUT>
__global__ __launch_bounds__(256) void gemm128(const u16* __restrict__ A, int lda,
                                               const u16* __restrict__ Bt, int ldb,
                                               const float* __restrict__ bias,
                                               float* __restrict__ Cf,
                                               u16* __restrict__ Cb, int ldc,
                                               int kslice) {
  __shared__ short sA[128 * 64];
  __shared__ short sB[128 * 64];
  const int tid = threadIdx.x;
  const int lane = tid & 63;
  const int wave = tid >> 6;
  const int bm = blockIdx.x * 128;
  const int bn = blockIdx.y * 128;
  const int k0 = blockIdx.z * kslice;
  const int wr = (wave >> 1) * 64;
  const int wc = (wave & 1) * 64;

  f32x4 acc[4][4] = {};

  const int srow = wave * 32 + (lane >> 3);               // staging row in tile
  const int scol = ((lane & 7) ^ (lane >> 3)) * 8;        // swizzled source col
  const u16* ag = A + (size_t)(bm + srow) * lda + scol;
  const u16* bg = Bt + (size_t)(bn + srow) * ldb + scol;
  short* sAw = &sA[(wave * 32) * 64];
  short* sBw = &sB[(wave * 32) * 64];

  const int swz = (lane & 7) << 3;                        // read-side XOR (shorts)

  for (int kt = k0; kt < k0 + kslice; kt += 64) {
#pragma unroll
    for (int j = 0; j < 4; ++j) {
      gload16(ag + (size_t)j * 8 * lda + kt, sAw + j * 8 * 64);
      gload16(bg + (size_t)j * 8 * ldb + kt, sBw + j * 8 * 64);
    }
    __syncthreads();
#pragma unroll
    for (int kk = 0; kk < 64; kk += 32) {
      const int kos = (kk + (lane >> 4) * 8) ^ swz;
      bf16x8 af[4], bfr[4];
#pragma unroll
      for (int m = 0; m < 4; ++m)
        af[m] = *(const bf16x8*)&sA[(wr + m * 16 + (lane & 15)) * 64 + kos];
#pragma unroll
      for (int n = 0; n < 4; ++n)
        bfr[n] = *(const bf16x8*)&sB[(wc + n * 16 + (lane & 15)) * 64 + kos];
#pragma unroll
      for (int m = 0; m < 4; ++m)
#pragma unroll
        for (int n = 0; n < 4; ++n)
          acc[m][n] = __builtin_amdgcn_mfma_f32_16x16x32_bf16(af[m], bfr[n], acc[m][n], 0, 0, 0);
    }
    __syncthreads();
  }

#pragma unroll
  for (int m = 0; m < 4; ++m) {
    const int row0 = bm + wr + m * 16 + (lane >> 4) * 4;
#pragma unroll
    for (int n = 0; n < 4; ++n) {
      const int col = bn + wc + n * 16 + (lane & 15);
      float badd = BIAS ? bias[col] : 0.f;
      f32x4 a4 = acc[m][n];
#pragma unroll
      for (int r = 0; r < 4; ++r) {
        float vv = a4[r] + badd;
        if (GELU) vv = 0.5f * vv * (1.f + erff(vv * 0.70710678118f));
        size_t idx = (size_t)(row0 + r) * ldc + col;
        if (OUT == 2) atomicAdd(&Cf[idx], vv);
        else if (OUT == 1) Cb[idx] = f2bfbits(vv);
        else Cf[idx] = vv;
      }
    }
  }
}

// ---------------------------------------------------------------------------
// Windowed (tridiagonal) attention for one head-group.
// One wave per (token, head-in-group). qkv: (NT, 3GN) bf16 [q|k|v blocks].
// ctx pre-offset to this group's column base; full row stride HK.
// ---------------------------------------------------------------------------
__global__ __launch_bounds__(256) void attn_window(const u16* __restrict__ qkv,
                                                   u16* __restrict__ ctx) {
  const int lane = threadIdx.x & 63;
  const int gw = blockIdx.x * 4 + (threadIdx.x >> 6);
  const int hh = gw % HG;
  const int t = gw / HG;
  const int s = t % S_;
  const size_t qb = (size_t)t * G3 + hh * K_ + lane * 8;

  float qf[8];
  {
    bf16x8 q8 = *(const bf16x8*)(qkv + qb);
#pragma unroll
    for (int e = 0; e < 8; ++e) qf[e] = bits2f((u16)q8[e]);
  }

  const bool val0 = (s > 0), val2 = (s < S_ - 1);
  float dot[3] = {0.f, 0.f, 0.f};
  float vf[3][8];
#pragma unroll
  for (int j = 0; j < 3; ++j) {
    if ((j == 0 && !val0) || (j == 2 && !val2)) continue;
    const size_t nb = qb + (size_t)(j - 1) * G3;
    bf16x8 k8 = *(const bf16x8*)(qkv + nb + GN);
    bf16x8 v8 = *(const bf16x8*)(qkv + nb + 2 * GN);
    float d = 0.f;
#pragma unroll
    for (int e = 0; e < 8; ++e) {
      d += qf[e] * bits2f((u16)k8[e]);
      vf[j][e] = bits2f((u16)v8[e]);
    }
    dot[j] = d;
  }
#pragma unroll
  for (int j = 0; j < 3; ++j) {
    float d = dot[j];
    for (int m = 32; m >= 1; m >>= 1) d += __shfl_xor(d, m);
    dot[j] = d;
  }
  const float scale = 0.044194173824159f;  // 1/sqrt(512)
  float sc[3];
  sc[0] = val0 ? dot[0] * scale : -1e30f;
  sc[1] = dot[1] * scale;
  sc[2] = val2 ? dot[2] * scale : -1e30f;
  float mx = fmaxf(sc[0], fmaxf(sc[1], sc[2]));
  float p[3], sum = 0.f;
#pragma unroll
  for (int j = 0; j < 3; ++j) {
    p[j] = (sc[j] > -1e29f) ? expf(sc[j] - mx) : 0.f;
    sum += p[j];
  }
  const float inv = 1.f / sum;
  float o[8] = {0.f, 0.f, 0.f, 0.f, 0.f, 0.f, 0.f, 0.f};
#pragma unroll
  for (int j = 0; j < 3; ++j) {
    if ((j == 0 && !val0) || (j == 2 && !val2)) continue;
    const float pj = p[j] * inv;
#pragma unroll
    for (int e = 0; e < 8; ++e) o[e] += pj * vf[j][e];
  }
  bf16x8 o8;
#pragma unroll
  for (int e = 0; e < 8; ++e) o8[e] = (short)f2bfbits(o[e]);
  *(bf16x8*)(ctx + (size_t)t * HK + hh * K_ + lane * 8) = o8;
}

// ---------------------------------------------------------------------------
// y = xres + yadd (+bias); out = LN(y)*gamma+beta -> fp32 (and optional bf16)
// one block (256 thr) per row of D=512
// ---------------------------------------------------------------------------
__global__ __launch_bounds__(256) void resid_ln(const float* __restrict__ xres,
                                                const float* __restrict__ yadd,
                                                const float* __restrict__ bias,
                                                const float* __restrict__ gamma,
                                                const float* __restrict__ beta,
                                                float* __restrict__ outf,
                                                u16* __restrict__ outb) {
  const int row = blockIdx.x;
  const int tid = threadIdx.x;
  const size_t base = (size_t)row * D_;
  float2 xv = ((const float2*)(xres + base))[tid];
  float2 yv = ((const float2*)(yadd + base))[tid];
  float y0 = xv.x + yv.x, y1 = xv.y + yv.y;
  if (bias) {
    float2 bv = ((const float2*)bias)[tid];
    y0 += bv.x; y1 += bv.y;
  }
  float s = y0 + y1, ss = y0 * y0 + y1 * y1;
  for (int m = 32; m >= 1; m >>= 1) { s += __shfl_xor(s, m); ss += __shfl_xor(ss, m); }
  __shared__ float red[8];
  const int wave = tid >> 6, lane = tid & 63;
  if (lane == 0) { red[wave] = s; red[4 + wave] = ss; }
  __syncthreads();
  s = red[0] + red[1] + red[2] + red[3];
  ss = red[4] + red[5] + red[6] + red[7];
  const float mean = s * (1.f / D_);
  const float var = ss * (1.f / D_) - mean * mean;
  const float rstd = rsqrtf(var + 1e-3f);
  float2 gv = ((const float2*)gamma)[tid];
  float2 bev = ((const float2*)beta)[tid];
  float o0 = (y0 - mean) * rstd * gv.x + bev.x;
  float o1 = (y1 - mean) * rstd * gv.y + bev.y;
  if (outf) { float2 of; of.x = o0; of.y = o1; ((float2*)(outf + base))[tid] = of; }
  if (outb) { ushort2 ob; ob.x = f2bfbits(o0); ob.y = f2bfbits(o1); ((ushort2*)(outb + base))[tid] = ob; }
}

// ---------------------------------------------------------------------------
extern "C" void kernel_launch(void* const* d_in, const int* in_sizes, int n_in,
                              void* d_out, int out_size, void* d_ws, size_t ws_size,
                              hipStream_t stream) {
  const float* x  = (const float*)d_in[0];
  const float* Wq = (const float*)d_in[1];
  const float* bq = (const float*)d_in[2];
  const float* Wk = (const float*)d_in[3];
  const float* bk = (const float*)d_in[4];
  const float* Wv = (const float*)d_in[5];
  const float* bv = (const float*)d_in[6];
  const float* Wo = (const float*)d_in[7];
  const float* bo = (const float*)d_in[8];
  const float* W1 = (const float*)d_in[9];
  const float* b1 = (const float*)d_in[10];
  const float* W2 = (const float*)d_in[11];
  const float* b2 = (const float*)d_in[12];
  const float* g1 = (const float*)d_in[13];
  const float* be1 = (const float*)d_in[14];
  const float* g2 = (const float*)d_in[15];
  const float* be2 = (const float*)d_in[16];
  float* out = (float*)d_out;

  char* w = (char*)d_ws;
  size_t o = 0;
  auto nxt = [&](size_t bytes) -> char* {
    char* p = w + o;
    o += (bytes + 255) & ~(size_t)255;
    return p;
  };
  u16* xb     = (u16*)nxt((size_t)NT * D_ * 2);
  u16* wqkvt  = (u16*)nxt((size_t)3 * HK * D_ * 2);   // [g][3][GN][D]
  u16* wot    = (u16*)nxt((size_t)D_ * HK * 2);
  u16* w1t    = (u16*)nxt((size_t)F_ * D_ * 2);
  u16* w2t    = (u16*)nxt((size_t)D_ * F_ * 2);
  float* qkvbias = (float*)nxt((size_t)NGROUP * G3 * 4);
  u16* qkvg   = (u16*)nxt((size_t)NT * G3 * 2);       // 48MB; aliased by hb later
  u16* ctxb   = (u16*)nxt((size_t)NT * HK * 2);       // 64MB
  float* attnf = (float*)nxt((size_t)NT * D_ * 4);    // 16MB; aliased by ffnf later
  float* out1f = (float*)nxt((size_t)NT * D_ * 4);
  u16* out1b   = (u16*)nxt((size_t)NT * D_ * 2);
  u16* hb      = (u16*)qkvg;    // alias: qkvg dead after attention
  float* ffnf  = attnf;         // alias: attnf dead after LN1

  // --- input/weight conversions ---
  conv_f32_bf16<<<dim3(NT * D_ / 4 / 256), 256, 0, stream>>>(x, xb, NT * D_ / 4);
  for (int g = 0; g < NGROUP; ++g) {
    transpose_f32_bf16<<<dim3(GN / 32, D_ / 32), 256, 0, stream>>>(
        Wq + g * GN, HK, wqkvt + ((size_t)(g * 3 + 0) * GN) * D_, D_, GN);
    transpose_f32_bf16<<<dim3(GN / 32, D_ / 32), 256, 0, stream>>>(
        Wk + g * GN, HK, wqkvt + ((size_t)(g * 3 + 1) * GN) * D_, D_, GN);
    transpose_f32_bf16<<<dim3(GN / 32, D_ / 32), 256, 0, stream>>>(
        Wv + g * GN, HK, wqkvt + ((size_t)(g * 3 + 2) * GN) * D_, D_, GN);
  }
  transpose_f32_bf16<<<dim3(D_ / 32, HK / 32), 256, 0, stream>>>(Wo, D_, wot, HK, D_);
  transpose_f32_bf16<<<dim3(F_ / 32, D_ / 32), 256, 0, stream>>>(W1, F_, w1t, D_, F_);
  transpose_f32_bf16<<<dim3(D_ / 32, F_ / 32), 256, 0, stream>>>(W2, D_, w2t, F_, D_);
  qkv_bias_cat<<<dim3(NGROUP * G3 / 256), 256, 0, stream>>>(bq, bk, bv, qkvbias);

  hipMemsetAsync(attnf, 0, (size_t)NT * D_ * 4, stream);

  // --- attention by head-groups: fused QKV gemm -> windowed attn ---
  for (int g = 0; g < NGROUP; ++g) {
    gemm128<1, 0, 1><<<dim3(NT / 128, G3 / 128), 256, 0, stream>>>(
        xb, D_, wqkvt + (size_t)g * G3 * D_, D_, qkvbias + g * G3,
        nullptr, qkvg, G3, D_);
    attn_window<<<dim3(NT * HG / 4), 256, 0, stream>>>(qkvg, ctxb + (size_t)g * HG * K_);
  }

  // --- WO: attnf += ctx @ Wo  (split-K=4, atomic) ---
  gemm128<0, 0, 2><<<dim3(NT / 128, D_ / 128, 4), 256, 0, stream>>>(
      ctxb, HK, wot, HK, nullptr, attnf, nullptr, D_, 1024);

  // --- LN1: out1 = LN(x + attn + bo) ---
  resid_ln<<<dim3(NT), 256, 0, stream>>>(x, attnf, bo, g1, be1, out1f, out1b);

  // --- FFN1: hb = gelu(out1 @ W1 + b1) ---
  gemm128<1, 1, 1><<<dim3(NT / 128, F_ / 128), 256, 0, stream>>>(
      out1b, D_, w1t, D_, b1, nullptr, hb, F_, D_);

  // --- FFN2: ffnf = hb @ W2 (split-K=2, atomic; b2 folded into LN2) ---
  hipMemsetAsync(ffnf, 0, (size_t)NT * D_ * 4, stream);
  gemm128<0, 0, 2><<<dim3(NT / 128, D_ / 128, 2), 256, 0, stream>>>(
      hb, F_, w2t, F_, nullptr, ffnf, nullptr, D_, 1024);

  // --- LN2: out = LN(out1 + ffn + b2) ---
  resid_ln<<<dim3(NT), 256, 0, stream>>>(out1f, ffnf, b2, g2, be2, out, nullptr);

  (void)in_sizes; (void)n_in; (void)out_size; (void)ws_size;
}

// Round 3
// 414.532 us; speedup vs baseline: 1.3437x; 1.2169x over previous
//
#include <hip/hip_runtime.h>
#include <hip/hip_bf16.h>
#include <math.h>

#define B_ 4
#define S_ 2048
#define D_ 512
#define H_ 8
#define K_ 512
#define F_ 2048
#define NT 8192     // B*S tokens
#define HK 4096     // H*K
#define HG 2        // heads per group
#define NGROUP 4    // H/HG
#define GN 1024     // HG*K columns per group
#define G3 3072     // 3*GN

typedef __attribute__((ext_vector_type(8))) short bf16x8;
typedef __attribute__((ext_vector_type(4))) float f32x4;
typedef unsigned short u16;

__device__ __forceinline__ float bits2f(u16 b) {
  union { unsigned u; float f; } c; c.u = ((unsigned)b) << 16; return c.f;
}
__device__ __forceinline__ u16 f2bfbits(float f) {
  union { float f; unsigned u; } c; c.f = f;
  unsigned r = c.u + 0x7fffu + ((c.u >> 16) & 1u);
  return (u16)(r >> 16);
}

__device__ __forceinline__ void gload16(const void* g, void* lds) {
  __builtin_amdgcn_global_load_lds(
      (const __attribute__((address_space(1))) unsigned int*)g,
      (__attribute__((address_space(3))) unsigned int*)lds, 16, 0, 0);
}

// ---------------------------------------------------------------------------
// fp32 -> bf16 elementwise (x conversion)
// ---------------------------------------------------------------------------
__global__ __launch_bounds__(256) void conv_f32_bf16(const float* __restrict__ in,
                                                     u16* __restrict__ out, int n4) {
  int i = blockIdx.x * 256 + threadIdx.x;
  if (i < n4) {
    float4 f = ((const float4*)in)[i];
    ushort4 o;
    o.x = f2bfbits(f.x); o.y = f2bfbits(f.y); o.z = f2bfbits(f.z); o.w = f2bfbits(f.w);
    ((ushort4*)out)[i] = o;
  }
}

// ---------------------------------------------------------------------------
// fp32 (rows x cols, leading dim ldin) -> bf16 transposed (cols x rows)
// ---------------------------------------------------------------------------
__global__ __launch_bounds__(256) void transpose_f32_bf16(const float* __restrict__ in,
                                                          int ldin,
                                                          u16* __restrict__ out,
                                                          int rows, int cols) {
  __shared__ float tile[32][33];
  const int tx = threadIdx.x & 31;
  const int ty = threadIdx.x >> 5;          // 0..7
  const int rb = blockIdx.y * 32;
  const int cb = blockIdx.x * 32;
  for (int i = ty; i < 32; i += 8)
    tile[i][tx] = in[(size_t)(rb + i) * ldin + cb + tx];
  __syncthreads();
  for (int i = ty; i < 32; i += 8)
    out[(size_t)(cb + i) * rows + rb + tx] = f2bfbits(tile[tx][i]);
}

// ---------------------------------------------------------------------------
// concat per-group qkv bias: o[g][part][GN], part 0=q 1=k 2=v
// ---------------------------------------------------------------------------
__global__ __launch_bounds__(256) void qkv_bias_cat(const float* __restrict__ bq,
                                                    const float* __restrict__ bk,
                                                    const float* __restrict__ bv,
                                                    float* __restrict__ o) {
  int i = blockIdx.x * 256 + threadIdx.x;   // < NGROUP*G3
  int g = i / G3, r = i % G3;
  int part = r / GN, off = r % GN;
  const float* src = (part == 0) ? bq : (part == 1) ? bk : bv;
  o[i] = src[g * GN + off];
}

// ---------------------------------------------------------------------------
// bf16 GEMM, 256x256 tile, BK=64, 8 waves (2M x 4N), double-buffered LDS,
// 2-phase pipeline: issue next tile's global_load_lds BEFORE computing the
// current tile; single __syncthreads() per K-tile (drains vmcnt + barrier).
// T2 XOR swizzle via pre-swizzled global source + swizzled LDS read.
// OUTBF: 1 = bf16 store (+bias)(+gelu), 0 = f32 partial store at
//        Cf + blockIdx.z * zstride (split-K).
// ---------------------------------------------------------------------------
template <int BIAS, int GELU, int OUTBF>
__global__ __launch_bounds__(512, 2) void gemm256(const u16* __restrict__ A, int lda,
                                                  const u16* __restrict__ Bt, int ldb,
                                                  const float* __restrict__ bias,
                                                  float* __restrict__ Cf, size_t zstride,
                                                  u16* __restrict__ Cb, int ldc,
                                                  int kslice) {
  __shared__ short lds[2][32768];   // [buf][ A:16384 shorts | B:16384 shorts ]
  const int tid = threadIdx.x;
  const int lane = tid & 63;
  const int wave = tid >> 6;        // 0..7
  const int bm = blockIdx.x * 256;
  const int bn = blockIdx.y * 256;
  const int k0 = blockIdx.z * kslice;

  const int wr = (wave >> 2) * 128; // wave row base (2 M-waves)
  const int wc = (wave & 3) * 64;   // wave col base (4 N-waves)

  f32x4 acc[8][4] = {};

  // staging geometry: per round, 512 threads move 64 rows x 64 cols (8KB).
  // wave w stages rows [w*8, w*8+8); lane l -> row w*8+(l>>3), chunk l&7.
  const int srow = wave * 8 + (lane >> 3);
  const int scol = ((lane & 7) ^ (lane >> 3)) * 8;    // swizzled source col
  const u16* ag = A + (size_t)(bm + srow) * lda + scol;
  const u16* bg = Bt + (size_t)(bn + srow) * ldb + scol;
  const int ldsbase = wave * 8 * 64;                  // shorts, wave-uniform

  auto STAGE = [&](int buf, int kt) {
    short* sA = &lds[buf][0];
    short* sB = &lds[buf][16384];
#pragma unroll
    for (int r = 0; r < 4; ++r)
      gload16(ag + (size_t)(r * 64) * lda + kt, sA + ldsbase + r * 64 * 64);
#pragma unroll
    for (int r = 0; r < 4; ++r)
      gload16(bg + (size_t)(r * 64) * ldb + kt, sB + ldsbase + r * 64 * 64);
  };

  auto COMPUTE = [&](int buf) {
    const short* sA = &lds[buf][0];
    const short* sB = &lds[buf][16384];
#pragma unroll
    for (int ks = 0; ks < 2; ++ks) {
      const int kos = (ks * 32 + (lane >> 4) * 8) ^ ((lane & 7) << 3);
      bf16x8 a[8], b[4];
#pragma unroll
      for (int m = 0; m < 8; ++m)
        a[m] = *(const bf16x8*)&sA[(wr + m * 16 + (lane & 15)) * 64 + kos];
#pragma unroll
      for (int n = 0; n < 4; ++n)
        b[n] = *(const bf16x8*)&sB[(wc + n * 16 + (lane & 15)) * 64 + kos];
#pragma unroll
      for (int m = 0; m < 8; ++m)
#pragma unroll
        for (int n = 0; n < 4; ++n)
          acc[m][n] = __builtin_amdgcn_mfma_f32_16x16x32_bf16(a[m], b[n], acc[m][n], 0, 0, 0);
    }
  };

  const int nt = kslice >> 6;
  STAGE(0, k0);
  __syncthreads();
  int cur = 0;
  for (int t = 0; t + 1 < nt; ++t) {
    STAGE(cur ^ 1, k0 + (t + 1) * 64);   // prefetch next tile (other buffer)
    COMPUTE(cur);                        // compute current under load latency
    __syncthreads();                     // vmcnt(0)+lgkmcnt(0)+barrier
    cur ^= 1;
  }
  COMPUTE(cur);

  float* Cfz = Cf + (size_t)blockIdx.z * zstride;
#pragma unroll
  for (int m = 0; m < 8; ++m) {
    const int row0 = bm + wr + m * 16 + (lane >> 4) * 4;
#pragma unroll
    for (int n = 0; n < 4; ++n) {
      const int col = bn + wc + n * 16 + (lane & 15);
      float badd = BIAS ? bias[col] : 0.f;
      f32x4 a4 = acc[m][n];
#pragma unroll
      for (int r = 0; r < 4; ++r) {
        float vv = a4[r] + badd;
        if (GELU) vv = 0.5f * vv * (1.f + erff(vv * 0.70710678118f));
        size_t idx = (size_t)(row0 + r) * ldc + col;
        if (OUTBF) Cb[idx] = f2bfbits(vv);
        else Cfz[idx] = vv;
      }
    }
  }
}

// ---------------------------------------------------------------------------
// Windowed (tridiagonal) attention for one head-group.
// One wave per (token, head-in-group). qkv: (NT, 3GN) bf16 [q|k|v blocks].
// ctx pre-offset to this group's column base; full row stride HK.
// ---------------------------------------------------------------------------
__global__ __launch_bounds__(256) void attn_window(const u16* __restrict__ qkv,
                                                   u16* __restrict__ ctx) {
  const int lane = threadIdx.x & 63;
  const int gw = blockIdx.x * 4 + (threadIdx.x >> 6);
  const int hh = gw % HG;
  const int t = gw / HG;
  const int s = t % S_;
  const size_t qb = (size_t)t * G3 + hh * K_ + lane * 8;

  float qf[8];
  {
    bf16x8 q8 = *(const bf16x8*)(qkv + qb);
#pragma unroll
    for (int e = 0; e < 8; ++e) qf[e] = bits2f((u16)q8[e]);
  }

  const bool val0 = (s > 0), val2 = (s < S_ - 1);
  float dot[3] = {0.f, 0.f, 0.f};
  float vf[3][8];
#pragma unroll
  for (int j = 0; j < 3; ++j) {
    if ((j == 0 && !val0) || (j == 2 && !val2)) continue;
    const size_t nb = qb + (size_t)(j - 1) * G3;
    bf16x8 k8 = *(const bf16x8*)(qkv + nb + GN);
    bf16x8 v8 = *(const bf16x8*)(qkv + nb + 2 * GN);
    float d = 0.f;
#pragma unroll
    for (int e = 0; e < 8; ++e) {
      d += qf[e] * bits2f((u16)k8[e]);
      vf[j][e] = bits2f((u16)v8[e]);
    }
    dot[j] = d;
  }
#pragma unroll
  for (int j = 0; j < 3; ++j) {
    float d = dot[j];
    for (int m = 32; m >= 1; m >>= 1) d += __shfl_xor(d, m);
    dot[j] = d;
  }
  const float scale = 0.044194173824159f;  // 1/sqrt(512)
  float sc[3];
  sc[0] = val0 ? dot[0] * scale : -1e30f;
  sc[1] = dot[1] * scale;
  sc[2] = val2 ? dot[2] * scale : -1e30f;
  float mx = fmaxf(sc[0], fmaxf(sc[1], sc[2]));
  float p[3], sum = 0.f;
#pragma unroll
  for (int j = 0; j < 3; ++j) {
    p[j] = (sc[j] > -1e29f) ? expf(sc[j] - mx) : 0.f;
    sum += p[j];
  }
  const float inv = 1.f / sum;
  float o[8] = {0.f, 0.f, 0.f, 0.f, 0.f, 0.f, 0.f, 0.f};
#pragma unroll
  for (int j = 0; j < 3; ++j) {
    if ((j == 0 && !val0) || (j == 2 && !val2)) continue;
    const float pj = p[j] * inv;
#pragma unroll
    for (int e = 0; e < 8; ++e) o[e] += pj * vf[j][e];
  }
  bf16x8 o8;
#pragma unroll
  for (int e = 0; e < 8; ++e) o8[e] = (short)f2bfbits(o[e]);
  *(bf16x8*)(ctx + (size_t)t * HK + hh * K_ + lane * 8) = o8;
}

// ---------------------------------------------------------------------------
// y = xres + sum(parts) (+bias); out = LN(y)*gamma+beta -> fp32 / bf16
// one block (256 thr) per row of D=512
// ---------------------------------------------------------------------------
__global__ __launch_bounds__(256) void resid_ln(const float* __restrict__ xres,
                                                const float* __restrict__ parts,
                                                int nparts, size_t pstride,
                                                const float* __restrict__ bias,
                                                const float* __restrict__ gamma,
                                                const float* __restrict__ beta,
                                                float* __restrict__ outf,
                                                u16* __restrict__ outb) {
  const int row = blockIdx.x;
  const int tid = threadIdx.x;
  const size_t base = (size_t)row * D_;
  float2 xv = ((const float2*)(xres + base))[tid];
  float y0 = xv.x, y1 = xv.y;
  for (int p = 0; p < nparts; ++p) {
    float2 pv = ((const float2*)(parts + p * pstride + base))[tid];
    y0 += pv.x; y1 += pv.y;
  }
  if (bias) {
    float2 bv = ((const float2*)bias)[tid];
    y0 += bv.x; y1 += bv.y;
  }
  float s = y0 + y1, ss = y0 * y0 + y1 * y1;
  for (int m = 32; m >= 1; m >>= 1) { s += __shfl_xor(s, m); ss += __shfl_xor(ss, m); }
  __shared__ float red[8];
  const int wave = tid >> 6, lane = tid & 63;
  if (lane == 0) { red[wave] = s; red[4 + wave] = ss; }
  __syncthreads();
  s = red[0] + red[1] + red[2] + red[3];
  ss = red[4] + red[5] + red[6] + red[7];
  const float mean = s * (1.f / D_);
  const float var = ss * (1.f / D_) - mean * mean;
  const float rstd = rsqrtf(var + 1e-3f);
  float2 gv = ((const float2*)gamma)[tid];
  float2 bev = ((const float2*)beta)[tid];
  float o0 = (y0 - mean) * rstd * gv.x + bev.x;
  float o1 = (y1 - mean) * rstd * gv.y + bev.y;
  if (outf) { float2 of; of.x = o0; of.y = o1; ((float2*)(outf + base))[tid] = of; }
  if (outb) { ushort2 ob; ob.x = f2bfbits(o0); ob.y = f2bfbits(o1); ((ushort2*)(outb + base))[tid] = ob; }
}

// ---------------------------------------------------------------------------
extern "C" void kernel_launch(void* const* d_in, const int* in_sizes, int n_in,
                              void* d_out, int out_size, void* d_ws, size_t ws_size,
                              hipStream_t stream) {
  const float* x  = (const float*)d_in[0];
  const float* Wq = (const float*)d_in[1];
  const float* bq = (const float*)d_in[2];
  const float* Wk = (const float*)d_in[3];
  const float* bk = (const float*)d_in[4];
  const float* Wv = (const float*)d_in[5];
  const float* bv = (const float*)d_in[6];
  const float* Wo = (const float*)d_in[7];
  const float* bo = (const float*)d_in[8];
  const float* W1 = (const float*)d_in[9];
  const float* b1 = (const float*)d_in[10];
  const float* W2 = (const float*)d_in[11];
  const float* b2 = (const float*)d_in[12];
  const float* g1 = (const float*)d_in[13];
  const float* be1 = (const float*)d_in[14];
  const float* g2 = (const float*)d_in[15];
  const float* be2 = (const float*)d_in[16];
  float* out = (float*)d_out;

  char* w = (char*)d_ws;
  size_t o = 0;
  auto nxt = [&](size_t bytes) -> char* {
    char* p = w + o;
    o += (bytes + 255) & ~(size_t)255;
    return p;
  };
  u16* xb     = (u16*)nxt((size_t)NT * D_ * 2);
  u16* wqkvt  = (u16*)nxt((size_t)3 * HK * D_ * 2);   // [g][3][GN][D]
  u16* wot    = (u16*)nxt((size_t)D_ * HK * 2);
  u16* w1t    = (u16*)nxt((size_t)F_ * D_ * 2);
  u16* w2t    = (u16*)nxt((size_t)D_ * F_ * 2);
  float* qkvbias = (float*)nxt((size_t)NGROUP * G3 * 4);
  u16* qkvg   = (u16*)nxt((size_t)NT * G3 * 2);       // 50.3MB
  char* extraA = nxt((size_t)NT * D_ * 4);            // 16.8MB pad after qkvg
  u16* ctxb   = (u16*)nxt((size_t)NT * HK * 2);       // 67.1MB
  float* out1f = (float*)nxt((size_t)NT * D_ * 4);
  u16* out1b   = (u16*)nxt((size_t)NT * D_ * 2);
  (void)extraA;
  // aliases (ordering-safe):
  //  woP  = qkvg..+67.1MB (qkvg 50.3 + extraA 16.8): 4x f32 WO partials.
  //         live: after attention (qkvg dead) until LN1.
  //  hb   = qkvg region (33.6MB): FFN1 output, live after LN1.
  //  ffnP = ctxb region (exactly 4x16.8MB): FFN2 partials, live after WO.
  float* woP  = (float*)qkvg;
  u16*   hb   = (u16*)qkvg;
  float* ffnP = (float*)ctxb;

  // --- input/weight conversions ---
  conv_f32_bf16<<<dim3(NT * D_ / 4 / 256), 256, 0, stream>>>(x, xb, NT * D_ / 4);
  for (int g = 0; g < NGROUP; ++g) {
    transpose_f32_bf16<<<dim3(GN / 32, D_ / 32), 256, 0, stream>>>(
        Wq + g * GN, HK, wqkvt + ((size_t)(g * 3 + 0) * GN) * D_, D_, GN);
    transpose_f32_bf16<<<dim3(GN / 32, D_ / 32), 256, 0, stream>>>(
        Wk + g * GN, HK, wqkvt + ((size_t)(g * 3 + 1) * GN) * D_, D_, GN);
    transpose_f32_bf16<<<dim3(GN / 32, D_ / 32), 256, 0, stream>>>(
        Wv + g * GN, HK, wqkvt + ((size_t)(g * 3 + 2) * GN) * D_, D_, GN);
  }
  transpose_f32_bf16<<<dim3(D_ / 32, HK / 32), 256, 0, stream>>>(Wo, D_, wot, HK, D_);
  transpose_f32_bf16<<<dim3(F_ / 32, D_ / 32), 256, 0, stream>>>(W1, F_, w1t, D_, F_);
  transpose_f32_bf16<<<dim3(D_ / 32, F_ / 32), 256, 0, stream>>>(W2, D_, w2t, F_, D_);
  qkv_bias_cat<<<dim3(NGROUP * G3 / 256), 256, 0, stream>>>(bq, bk, bv, qkvbias);

  // --- attention by head-groups: fused QKV gemm -> windowed attn ---
  for (int g = 0; g < NGROUP; ++g) {
    gemm256<1, 0, 1><<<dim3(32, G3 / 256, 1), 512, 0, stream>>>(
        xb, D_, wqkvt + (size_t)g * G3 * D_, D_, qkvbias + g * G3,
        nullptr, 0, qkvg, G3, D_);
    attn_window<<<dim3(NT * HG / 4), 256, 0, stream>>>(qkvg, ctxb + (size_t)g * HG * K_);
  }

  // --- WO: woP[z] = ctx @ Wo (split-K=4 partials, no atomics) ---
  gemm256<0, 0, 0><<<dim3(32, 2, 4), 512, 0, stream>>>(
      ctxb, HK, wot, HK, nullptr, woP, (size_t)NT * D_, nullptr, D_, 1024);

  // --- LN1: out1 = LN(x + sum(woP) + bo) ---
  resid_ln<<<dim3(NT), 256, 0, stream>>>(x, woP, 4, (size_t)NT * D_, bo,
                                         g1, be1, out1f, out1b);

  // --- FFN1: hb = gelu(out1 @ W1 + b1) ---
  gemm256<1, 1, 1><<<dim3(32, F_ / 256, 1), 512, 0, stream>>>(
      out1b, D_, w1t, D_, b1, nullptr, 0, hb, F_, D_);

  // --- FFN2: ffnP[z] = hb @ W2 (split-K=4 partials; b2 folded into LN2) ---
  gemm256<0, 0, 0><<<dim3(32, 2, 4), 512, 0, stream>>>(
      hb, F_, w2t, F_, nullptr, ffnP, (size_t)NT * D_, nullptr, D_, 512);

  // --- LN2: out = LN(out1 + sum(ffnP) + b2) ---
  resid_ln<<<dim3(NT), 256, 0, stream>>>(out1f, ffnP, 4, (size_t)NT * D_, b2,
                                         g2, be2, out, nullptr);

  (void)in_sizes; (void)n_in; (void)out_size; (void)ws_size;
}